// Round 9
// baseline (163.257 us; speedup 1.0000x reference)
//
#include <hip/hip_runtime.h>

#define WW 512
#define HH 512
#define NPLANES 64   // B*C = 16*4
#define NCH 4
#define NSTRIP 8     // 64-row strips per plane (4 waves x 16 rows per block)

// e(x) = 2^(-14.43*x + 7.21); sigmoid((x-0.5)*10) = 1/(1+e(x))
__device__ __forceinline__ float expu(float x) {
    return __builtin_amdgcn_exp2f(__builtin_fmaf(x, -14.4269504089f, 7.2134752044f));
}
__device__ __forceinline__ float sigf(float x) {
    return __builtin_amdgcn_rcpf(1.0f + expu(x));
}
// sum of 1/p_i over 4 values with ONE rcp
__device__ __forceinline__ float sum4sig(float p0, float p1, float p2, float p3) {
    float q01 = p0 * p1, q23 = p2 * p3;
    float inv = __builtin_amdgcn_rcpf(q01 * q23);
    return __builtin_fmaf(p0 + p1, q23, (p2 + p3) * q01) * inv;
}
// individual reciprocals of 4 values with ONE rcp (batch inversion)
__device__ __forceinline__ void inv4(float p0, float p1, float p2, float p3,
                                     float& r0, float& r1, float& r2, float& r3) {
    float q01 = p0 * p1, q23 = p2 * p3;
    float inv = __builtin_amdgcn_rcpf(q01 * q23);
    float i01 = q23 * inv, i23 = q01 * inv;   // 1/(p0 p1), 1/(p2 p3)
    r0 = p1 * i01; r1 = p0 * i01;
    r2 = p3 * i23; r3 = p2 * i23;
}

// Stage 1 -- ZERO-DS-LOOP experiment.
// R8 proved instruction issue is not the wall (VALUBusy 43->34%, dur flat).
// Only loop component never removed: 3 wave shuffles/iter (ds_bpermute,
// ~120cy latency each + lgkmcnt(0) waits at fixed points for every wave --
// correlated serialization; and if any load lowered flat, lgkmcnt(0) also
// drains the row prefetch, explaining R3/R4 prefetch nulls). This version has
// NO cross-lane ops in the loop:
//  - lv/rv from 2 clamped scalar halo loads of the raw row (L1/L2-hot) + sigf
//  - no row-sum fold: store all 64 per-lane partials (256B/row contiguous);
//    stage2 sums 64.
// Diagnostic: SQ_LDS_BANK_CONFLICT (pinned 65536 all rounds) should -> ~0.
__global__ __launch_bounds__(256, 4)
void k_stage1(const float* __restrict__ inp, const float* __restrict__ tgt,
              float* __restrict__ colpart, float* __restrict__ rowsum64,
              float* __restrict__ out) {
    const int bid    = blockIdx.x;
    const int tensor = bid >> 9;          // 0..1
    const int plane  = (bid >> 3) & 63;   // 0..63
    const int s      = bid & 7;           // 0..7 (64-row strip)
    const int tid    = threadIdx.x;
    const int wave   = tid >> 6;          // 0..3
    const int lane   = tid & 63;

    if (bid == 0 && tid == 0) out[0] = 0.0f;  // zero-init for stage-2 atomics

    const float* __restrict__ base =
        (tensor == 0 ? inp : tgt) + (size_t)plane * (HH * WW);
    const int r0    = s * 64 + wave * 16;
    const int r1    = r0 + 16;
    const int cbase = lane * 8;
    // clamped halo column indices (values for the clamped lanes are replaced
    // by the zero-pad below, the clamp only keeps addresses in bounds)
    const int loH = (lane == 0)  ? 0   : cbase - 1;
    const int hiH = (lane == 63) ? 511 : cbase + 8;

    float p[8], c[8], cacc[8];
    #pragma unroll
    for (int k = 0; k < 8; ++k) cacc[k] = 0.0f;

    // prologue: p = sig(row r0-1) (zero-pad), c = sig(row r0)
    if (r0 == 0) {
        #pragma unroll
        for (int k = 0; k < 8; ++k) p[k] = 0.0f;
    } else {
        const float4* p4 = reinterpret_cast<const float4*>(base + (size_t)(r0 - 1) * WW + cbase);
        float4 a0 = p4[0], b0 = p4[1];
        p[0]=sigf(a0.x); p[1]=sigf(a0.y); p[2]=sigf(a0.z); p[3]=sigf(a0.w);
        p[4]=sigf(b0.x); p[5]=sigf(b0.y); p[6]=sigf(b0.z); p[7]=sigf(b0.w);
    }
    {
        const float4* p4 = reinterpret_cast<const float4*>(base + (size_t)r0 * WW + cbase);
        float4 a0 = p4[0], b0 = p4[1];
        c[0]=sigf(a0.x); c[1]=sigf(a0.y); c[2]=sigf(a0.z); c[3]=sigf(a0.w);
        c[4]=sigf(b0.x); c[5]=sigf(b0.y); c[6]=sigf(b0.z); c[7]=sigf(b0.w);
    }
    // halo raw values for row r0
    float hl = base[(size_t)r0 * WW + loH];
    float hr = base[(size_t)r0 * WW + hiH];

    // 1-deep prefetch: raw row r0+1 (always exists: max r0 = 496)
    float4 a, b;
    {
        const float4* p4 = reinterpret_cast<const float4*>(base + (size_t)(r0 + 1) * WW + cbase);
        a = p4[0]; b = p4[1];
    }

    const float* rowp2 = base + (size_t)(r0 + 2) * WW + cbase;
    float* rsp = rowsum64 + ((size_t)tensor * NPLANES + plane) * (HH * 64)
                          + (size_t)r0 * 64 + lane;

    for (int r = r0; r < r1; ++r, rowp2 += WW, rsp += 64) {
        // 1) issue next-next row load (row r+2, consumed at iter r+1) and the
        //    halo loads for row r+1 (consumed at iter r+1)
        float4 na, nb;
        if (r + 2 < HH) {
            const float4* p4 = reinterpret_cast<const float4*>(rowp2);
            na = p4[0]; nb = p4[1];
        } else {
            na = make_float4(0.f,0.f,0.f,0.f); nb = na;
        }
        const int rn = (r + 1 < HH) ? (r + 1) : (HH - 1);   // clamp (last iter only)
        float nhl = base[(size_t)rn * WW + loH];
        float nhr = base[(size_t)rn * WW + hiH];

        // 2) horizontal bounds on row r -- NO cross-lane ops:
        //    lv/rv recomputed from raw halos (zero-pad at image edges)
        float lv = (lane == 0)  ? 0.0f : sigf(hl);
        float rv = (lane == 63) ? 0.0f : sigf(hr);

        float h0 = 1.0f + expu(fabsf(c[1] - lv));
        float h1 = 1.0f + expu(fabsf(c[2] - c[0]));
        float h2 = 1.0f + expu(fabsf(c[3] - c[1]));
        float h3 = 1.0f + expu(fabsf(c[4] - c[2]));
        float h4 = 1.0f + expu(fabsf(c[5] - c[3]));
        float h5 = 1.0f + expu(fabsf(c[6] - c[4]));
        float h6 = 1.0f + expu(fabsf(c[7] - c[5]));
        float h7 = 1.0f + expu(fabsf(rv   - c[6]));
        float hp = sum4sig(h0, h1, h2, h3) + sum4sig(h4, h5, h6, h7);
        *rsp = hp;   // 64 per-lane partials, 256B contiguous per row

        // 3) convert raw row r+1 (loaded last iteration)
        float nxt[8];
        if (r + 1 < HH) {
            float q0 = 1.0f + expu(a.x), q1 = 1.0f + expu(a.y);
            float q2 = 1.0f + expu(a.z), q3 = 1.0f + expu(a.w);
            float q4 = 1.0f + expu(b.x), q5 = 1.0f + expu(b.y);
            float q6 = 1.0f + expu(b.z), q7 = 1.0f + expu(b.w);
            inv4(q0, q1, q2, q3, nxt[0], nxt[1], nxt[2], nxt[3]);
            inv4(q4, q5, q6, q7, nxt[4], nxt[5], nxt[6], nxt[7]);
        } else {
            #pragma unroll
            for (int k = 0; k < 8; ++k) nxt[k] = 0.0f;  // zero-pad row H
        }

        // 4) vertical bounds: batch inversion, 8 exp + 2 rcp
        {
            float v0 = 1.0f + expu(fabsf(nxt[0] - p[0]));
            float v1 = 1.0f + expu(fabsf(nxt[1] - p[1]));
            float v2 = 1.0f + expu(fabsf(nxt[2] - p[2]));
            float v3 = 1.0f + expu(fabsf(nxt[3] - p[3]));
            float v4 = 1.0f + expu(fabsf(nxt[4] - p[4]));
            float v5 = 1.0f + expu(fabsf(nxt[5] - p[5]));
            float v6 = 1.0f + expu(fabsf(nxt[6] - p[6]));
            float v7 = 1.0f + expu(fabsf(nxt[7] - p[7]));
            float s0, s1, s2, s3, s4, s5, s6, s7;
            inv4(v0, v1, v2, v3, s0, s1, s2, s3);
            inv4(v4, v5, v6, v7, s4, s5, s6, s7);
            cacc[0] += s0; cacc[1] += s1; cacc[2] += s2; cacc[3] += s3;
            cacc[4] += s4; cacc[5] += s5; cacc[6] += s6; cacc[7] += s7;
        }

        // rotate window + advance prefetch buffers
        #pragma unroll
        for (int k = 0; k < 8; ++k) { p[k] = c[k]; c[k] = nxt[k]; }
        a = na; b = nb;
        hl = nhl; hr = nhr;
    }

    // combine column partials across the 4 waves of this block
    __shared__ float cl[4][WW];
    #pragma unroll
    for (int k = 0; k < 8; ++k) cl[wave][cbase + k] = cacc[k];
    __syncthreads();

    float* __restrict__ cp_out =
        colpart + (((size_t)tensor * NPLANES + plane) * NSTRIP + s) * WW;
    for (int cc = tid; cc < WW; cc += 256)
        cp_out[cc] = cl[0][cc] + cl[1][cc] + cl[2][cc] + cl[3][cc];
}

// logical sobel-source value: S(0)=512*sig(0), S(j)=sum[j-1], 0 outside [0,512)
__device__ __forceinline__ float Sval(const float* s, int j, float s0) {
    if (j < 0 || j >= 512) return 0.0f;
    if (j == 0) return s0;
    return s[j - 1];
}
__device__ __forceinline__ float term(const float* s, int j, float s0) {
    return fabsf(Sval(s, j + 1, s0) - Sval(s, j - 1, s0));
}

// Stage 2, split by (plane, direction): 128 blocks. dir=0 reduces colpart,
// dir=1 reduces rowsum64 (64 partials per row, float4 x16).
__global__ __launch_bounds__(256)
void k_stage2(const float* __restrict__ colpart, const float* __restrict__ rowsum64,
              const float* __restrict__ weight, float* __restrict__ out) {
    __shared__ float sI[WW], sT[WW];
    const int p   = blockIdx.x >> 1;   // plane = b*4 + c
    const int dir = blockIdx.x & 1;    // 0: x (cols), 1: y (rows)
    const int tid = threadIdx.x;

    if (dir == 0) {
        for (int c = tid; c < WW; c += 256) {
            const float* a = colpart + (((size_t)0 * NPLANES + p) * NSTRIP) * WW + c;
            const float* b = colpart + (((size_t)1 * NPLANES + p) * NSTRIP) * WW + c;
            float sa = 0.f, sb = 0.f;
            #pragma unroll
            for (int i = 0; i < NSTRIP; ++i) { sa += a[i * WW]; sb += b[i * WW]; }
            sI[c] = sa;
            sT[c] = sb;
        }
    } else {
        for (int c = tid; c < WW; c += 256) {
            const float4* ra = reinterpret_cast<const float4*>(
                rowsum64 + ((size_t)0 * NPLANES + p) * (HH * 64) + (size_t)c * 64);
            const float4* rb = reinterpret_cast<const float4*>(
                rowsum64 + ((size_t)1 * NPLANES + p) * (HH * 64) + (size_t)c * 64);
            float sra = 0.f, srb = 0.f;
            #pragma unroll
            for (int i = 0; i < 16; ++i) {
                float4 va = ra[i], vb = rb[i];
                sra += (va.x + va.y) + (va.z + va.w);
                srb += (vb.x + vb.y) + (vb.z + vb.w);
            }
            sI[c] = sra;
            sT[c] = srb;
        }
    }
    __syncthreads();

    // 512 * sigmoid(-5)
    const float s0 = 3.4267396732f;

    float sumI = 0.f, sumT = 0.f;
    for (int j = tid; j < WW; j += 256) {
        sumI += term(sI, j, s0);
        sumT += term(sT, j, s0);
    }
    #pragma unroll
    for (int off = 32; off >= 1; off >>= 1) {
        sumI += __shfl_xor(sumI, off);
        sumT += __shfl_xor(sumT, off);
    }
    __shared__ float red[4][2];
    const int wave = tid >> 6, lane = tid & 63;
    if (lane == 0) { red[wave][0] = sumI; red[wave][1] = sumT; }
    __syncthreads();
    if (tid == 0) {
        float I = 0.f, T = 0.f;
        for (int w2 = 0; w2 < 4; ++w2) { I += red[w2][0]; T += red[w2][1]; }
        I *= 0.25f; T *= 0.25f;
        const float wgt = weight[p & (NCH - 1)];
        float loss = 0.5f * fabsf((I - T) * wgt);
        atomicAdd(out, loss * (1.0f / NPLANES));
    }
}

extern "C" void kernel_launch(void* const* d_in, const int* in_sizes, int n_in,
                              void* d_out, int out_size, void* d_ws, size_t ws_size,
                              hipStream_t stream) {
    const float* inp = (const float*)d_in[0];
    const float* tgt = (const float*)d_in[1];
    const float* wgt = (const float*)d_in[2];
    float* ws = (float*)d_ws;

    // ws layout (floats):
    float* colpart  = ws;                      // [2][64][8][512]   = 524288
    float* rowsum64 = ws + 524288;             // [2][64][512][64]  = 4194304
    // total 4718592 floats = 18.9 MB

    k_stage1<<<1024, 256, 0, stream>>>(inp, tgt, colpart, rowsum64, (float*)d_out);
    k_stage2<<<128, 256, 0, stream>>>(colpart, rowsum64, wgt, (float*)d_out);
}

// Round 10
// 163.057 us; speedup vs baseline: 1.0012x; 1.0012x over previous
//
#include <hip/hip_runtime.h>

#define WW 512
#define HH 512
#define NPLANES 64   // B*C = 16*4
#define NCH 4
#define NSTRIP 8     // 64-row strips per plane (4 waves x 16 rows per block)

// e(x) = 2^(-14.43*x + 7.21); sigmoid((x-0.5)*10) = 1/(1+e(x))
__device__ __forceinline__ float expu(float x) {          // trans-pipe exp2
    return __builtin_amdgcn_exp2f(__builtin_fmaf(x, -14.4269504089f, 7.2134752044f));
}
// VALU-only exp2 for x in [-8.5, 8.5]: range-reduce + degree-5 poly + exponent
// assemble. ~2e-6 rel error. 10 VALU ops, ZERO trans ops -- offloads the
// (theorized) saturated transcendental unit onto the ~43%-busy VALU pipe.
__device__ __forceinline__ float exp2p(float x) {
    float n = __builtin_rintf(x);            // v_rndne_f32
    float f = x - n;                         // f in [-0.5, 0.5]
    float p = 1.3333649840e-3f;              // ~ln2^5/120
    p = __builtin_fmaf(p, f, 9.6181291076e-3f);   // ln2^4/24
    p = __builtin_fmaf(p, f, 5.5504108665e-2f);   // ln2^3/6
    p = __builtin_fmaf(p, f, 2.4022650696e-1f);   // ln2^2/2
    p = __builtin_fmaf(p, f, 6.9314718056e-1f);   // ln2
    p = __builtin_fmaf(p, f, 1.0f);
    int e = (((int)n) + 127) << 23;          // 2^n as float bits
    return p * __int_as_float(e);
}
__device__ __forceinline__ float expuv(float t) {         // VALU-only expu
    return exp2p(__builtin_fmaf(t, -14.4269504089f, 7.2134752044f));
}
__device__ __forceinline__ float sigf(float x) {
    return __builtin_amdgcn_rcpf(1.0f + expu(x));
}
// sum of 1/p_i over 4 values with ONE rcp
__device__ __forceinline__ float sum4sig(float p0, float p1, float p2, float p3) {
    float q01 = p0 * p1, q23 = p2 * p3;
    float inv = __builtin_amdgcn_rcpf(q01 * q23);
    return __builtin_fmaf(p0 + p1, q23, (p2 + p3) * q01) * inv;
}
// individual reciprocals of 4 values with ONE rcp (batch inversion)
__device__ __forceinline__ void inv4(float p0, float p1, float p2, float p3,
                                     float& r0, float& r1, float& r2, float& r3) {
    float q01 = p0 * p1, q23 = p2 * p3;
    float inv = __builtin_amdgcn_rcpf(q01 * q23);
    float i01 = q23 * inv, i23 = q01 * inv;   // 1/(p0 p1), 1/(p2 p3)
    r0 = p1 * i01; r1 = p0 * i01;
    r2 = p3 * i23; r3 = p2 * i23;
}

// Stage 1 -- TRANS-PIPE OFFLOAD experiment (R9 base, single variable).
// Ledger: occupancy x2, rcp -75%, VALU -20% (VALUBusy 43->34, dur FLAT),
// prefetch, L3-resident, zero-DS -- all null. The ONE constant across all
// rounds: ~26 v_exp_f32/iter. If exp is ~16cy/wave64 (1/16-rate) and rcp ~4cy,
// trans demand = 26*16+8*4 ~ 450cy/wave-iter == the measured wall, and every
// null is postdicted. Test: move the 8 vertical-bound exps to VALU-only
// exp2p (poly). Balance: trans 448->320cy, VALU 192->352cy -> wall -20%.
__global__ __launch_bounds__(256, 4)
void k_stage1(const float* __restrict__ inp, const float* __restrict__ tgt,
              float* __restrict__ colpart, float* __restrict__ rowsum64,
              float* __restrict__ out) {
    const int bid    = blockIdx.x;
    const int tensor = bid >> 9;          // 0..1
    const int plane  = (bid >> 3) & 63;   // 0..63
    const int s      = bid & 7;           // 0..7 (64-row strip)
    const int tid    = threadIdx.x;
    const int wave   = tid >> 6;          // 0..3
    const int lane   = tid & 63;

    if (bid == 0 && tid == 0) out[0] = 0.0f;  // zero-init for stage-2 atomics

    const float* __restrict__ base =
        (tensor == 0 ? inp : tgt) + (size_t)plane * (HH * WW);
    const int r0    = s * 64 + wave * 16;
    const int r1    = r0 + 16;
    const int cbase = lane * 8;
    // clamped halo column indices (clamped lanes overwritten by zero-pad)
    const int loH = (lane == 0)  ? 0   : cbase - 1;
    const int hiH = (lane == 63) ? 511 : cbase + 8;

    float p[8], c[8], cacc[8];
    #pragma unroll
    for (int k = 0; k < 8; ++k) cacc[k] = 0.0f;

    // prologue: p = sig(row r0-1) (zero-pad), c = sig(row r0)
    if (r0 == 0) {
        #pragma unroll
        for (int k = 0; k < 8; ++k) p[k] = 0.0f;
    } else {
        const float4* p4 = reinterpret_cast<const float4*>(base + (size_t)(r0 - 1) * WW + cbase);
        float4 a0 = p4[0], b0 = p4[1];
        p[0]=sigf(a0.x); p[1]=sigf(a0.y); p[2]=sigf(a0.z); p[3]=sigf(a0.w);
        p[4]=sigf(b0.x); p[5]=sigf(b0.y); p[6]=sigf(b0.z); p[7]=sigf(b0.w);
    }
    {
        const float4* p4 = reinterpret_cast<const float4*>(base + (size_t)r0 * WW + cbase);
        float4 a0 = p4[0], b0 = p4[1];
        c[0]=sigf(a0.x); c[1]=sigf(a0.y); c[2]=sigf(a0.z); c[3]=sigf(a0.w);
        c[4]=sigf(b0.x); c[5]=sigf(b0.y); c[6]=sigf(b0.z); c[7]=sigf(b0.w);
    }
    // halo raw values for row r0
    float hl = base[(size_t)r0 * WW + loH];
    float hr = base[(size_t)r0 * WW + hiH];

    // 1-deep prefetch: raw row r0+1 (always exists: max r0 = 496)
    float4 a, b;
    {
        const float4* p4 = reinterpret_cast<const float4*>(base + (size_t)(r0 + 1) * WW + cbase);
        a = p4[0]; b = p4[1];
    }

    const float* rowp2 = base + (size_t)(r0 + 2) * WW + cbase;
    float* rsp = rowsum64 + ((size_t)tensor * NPLANES + plane) * (HH * 64)
                          + (size_t)r0 * 64 + lane;

    for (int r = r0; r < r1; ++r, rowp2 += WW, rsp += 64) {
        // 1) issue next-next row load (row r+2) + halo loads for row r+1
        float4 na, nb;
        if (r + 2 < HH) {
            const float4* p4 = reinterpret_cast<const float4*>(rowp2);
            na = p4[0]; nb = p4[1];
        } else {
            na = make_float4(0.f,0.f,0.f,0.f); nb = na;
        }
        const int rn = (r + 1 < HH) ? (r + 1) : (HH - 1);
        float nhl = base[(size_t)rn * WW + loH];
        float nhr = base[(size_t)rn * WW + hiH];

        // 2) horizontal bounds on row r (trans-pipe exps, unchanged)
        float lv = (lane == 0)  ? 0.0f : sigf(hl);
        float rv = (lane == 63) ? 0.0f : sigf(hr);

        float h0 = 1.0f + expu(fabsf(c[1] - lv));
        float h1 = 1.0f + expu(fabsf(c[2] - c[0]));
        float h2 = 1.0f + expu(fabsf(c[3] - c[1]));
        float h3 = 1.0f + expu(fabsf(c[4] - c[2]));
        float h4 = 1.0f + expu(fabsf(c[5] - c[3]));
        float h5 = 1.0f + expu(fabsf(c[6] - c[4]));
        float h6 = 1.0f + expu(fabsf(c[7] - c[5]));
        float h7 = 1.0f + expu(fabsf(rv   - c[6]));
        float hp = sum4sig(h0, h1, h2, h3) + sum4sig(h4, h5, h6, h7);
        *rsp = hp;   // 64 per-lane partials, 256B contiguous per row

        // 3) convert raw row r+1 (trans-pipe exps, unchanged)
        float nxt[8];
        if (r + 1 < HH) {
            float q0 = 1.0f + expu(a.x), q1 = 1.0f + expu(a.y);
            float q2 = 1.0f + expu(a.z), q3 = 1.0f + expu(a.w);
            float q4 = 1.0f + expu(b.x), q5 = 1.0f + expu(b.y);
            float q6 = 1.0f + expu(b.z), q7 = 1.0f + expu(b.w);
            inv4(q0, q1, q2, q3, nxt[0], nxt[1], nxt[2], nxt[3]);
            inv4(q4, q5, q6, q7, nxt[4], nxt[5], nxt[6], nxt[7]);
        } else {
            #pragma unroll
            for (int k = 0; k < 8; ++k) nxt[k] = 0.0f;  // zero-pad row H
        }

        // 4) vertical bounds: exps moved to the VALU pipe (expuv = poly exp2)
        {
            float v0 = 1.0f + expuv(fabsf(nxt[0] - p[0]));
            float v1 = 1.0f + expuv(fabsf(nxt[1] - p[1]));
            float v2 = 1.0f + expuv(fabsf(nxt[2] - p[2]));
            float v3 = 1.0f + expuv(fabsf(nxt[3] - p[3]));
            float v4 = 1.0f + expuv(fabsf(nxt[4] - p[4]));
            float v5 = 1.0f + expuv(fabsf(nxt[5] - p[5]));
            float v6 = 1.0f + expuv(fabsf(nxt[6] - p[6]));
            float v7 = 1.0f + expuv(fabsf(nxt[7] - p[7]));
            float s0, s1, s2, s3, s4, s5, s6, s7;
            inv4(v0, v1, v2, v3, s0, s1, s2, s3);
            inv4(v4, v5, v6, v7, s4, s5, s6, s7);
            cacc[0] += s0; cacc[1] += s1; cacc[2] += s2; cacc[3] += s3;
            cacc[4] += s4; cacc[5] += s5; cacc[6] += s6; cacc[7] += s7;
        }

        // rotate window + advance prefetch buffers
        #pragma unroll
        for (int k = 0; k < 8; ++k) { p[k] = c[k]; c[k] = nxt[k]; }
        a = na; b = nb;
        hl = nhl; hr = nhr;
    }

    // combine column partials across the 4 waves of this block
    __shared__ float cl[4][WW];
    #pragma unroll
    for (int k = 0; k < 8; ++k) cl[wave][cbase + k] = cacc[k];
    __syncthreads();

    float* __restrict__ cp_out =
        colpart + (((size_t)tensor * NPLANES + plane) * NSTRIP + s) * WW;
    for (int cc = tid; cc < WW; cc += 256)
        cp_out[cc] = cl[0][cc] + cl[1][cc] + cl[2][cc] + cl[3][cc];
}

// logical sobel-source value: S(0)=512*sig(0), S(j)=sum[j-1], 0 outside [0,512)
__device__ __forceinline__ float Sval(const float* s, int j, float s0) {
    if (j < 0 || j >= 512) return 0.0f;
    if (j == 0) return s0;
    return s[j - 1];
}
__device__ __forceinline__ float term(const float* s, int j, float s0) {
    return fabsf(Sval(s, j + 1, s0) - Sval(s, j - 1, s0));
}

// Stage 2, split by (plane, direction): 128 blocks. dir=0 reduces colpart,
// dir=1 reduces rowsum64 (64 partials per row, float4 x16).
__global__ __launch_bounds__(256)
void k_stage2(const float* __restrict__ colpart, const float* __restrict__ rowsum64,
              const float* __restrict__ weight, float* __restrict__ out) {
    __shared__ float sI[WW], sT[WW];
    const int p   = blockIdx.x >> 1;   // plane = b*4 + c
    const int dir = blockIdx.x & 1;    // 0: x (cols), 1: y (rows)
    const int tid = threadIdx.x;

    if (dir == 0) {
        for (int c = tid; c < WW; c += 256) {
            const float* a = colpart + (((size_t)0 * NPLANES + p) * NSTRIP) * WW + c;
            const float* b = colpart + (((size_t)1 * NPLANES + p) * NSTRIP) * WW + c;
            float sa = 0.f, sb = 0.f;
            #pragma unroll
            for (int i = 0; i < NSTRIP; ++i) { sa += a[i * WW]; sb += b[i * WW]; }
            sI[c] = sa;
            sT[c] = sb;
        }
    } else {
        for (int c = tid; c < WW; c += 256) {
            const float4* ra = reinterpret_cast<const float4*>(
                rowsum64 + ((size_t)0 * NPLANES + p) * (HH * 64) + (size_t)c * 64);
            const float4* rb = reinterpret_cast<const float4*>(
                rowsum64 + ((size_t)1 * NPLANES + p) * (HH * 64) + (size_t)c * 64);
            float sra = 0.f, srb = 0.f;
            #pragma unroll
            for (int i = 0; i < 16; ++i) {
                float4 va = ra[i], vb = rb[i];
                sra += (va.x + va.y) + (va.z + va.w);
                srb += (vb.x + vb.y) + (vb.z + vb.w);
            }
            sI[c] = sra;
            sT[c] = srb;
        }
    }
    __syncthreads();

    // 512 * sigmoid(-5)
    const float s0 = 3.4267396732f;

    float sumI = 0.f, sumT = 0.f;
    for (int j = tid; j < WW; j += 256) {
        sumI += term(sI, j, s0);
        sumT += term(sT, j, s0);
    }
    #pragma unroll
    for (int off = 32; off >= 1; off >>= 1) {
        sumI += __shfl_xor(sumI, off);
        sumT += __shfl_xor(sumT, off);
    }
    __shared__ float red[4][2];
    const int wave = tid >> 6, lane = tid & 63;
    if (lane == 0) { red[wave][0] = sumI; red[wave][1] = sumT; }
    __syncthreads();
    if (tid == 0) {
        float I = 0.f, T = 0.f;
        for (int w2 = 0; w2 < 4; ++w2) { I += red[w2][0]; T += red[w2][1]; }
        I *= 0.25f; T *= 0.25f;
        const float wgt = weight[p & (NCH - 1)];
        float loss = 0.5f * fabsf((I - T) * wgt);
        atomicAdd(out, loss * (1.0f / NPLANES));
    }
}

extern "C" void kernel_launch(void* const* d_in, const int* in_sizes, int n_in,
                              void* d_out, int out_size, void* d_ws, size_t ws_size,
                              hipStream_t stream) {
    const float* inp = (const float*)d_in[0];
    const float* tgt = (const float*)d_in[1];
    const float* wgt = (const float*)d_in[2];
    float* ws = (float*)d_ws;

    // ws layout (floats):
    float* colpart  = ws;                      // [2][64][8][512]   = 524288
    float* rowsum64 = ws + 524288;             // [2][64][512][64]  = 4194304
    // total 4718592 floats = 18.9 MB

    k_stage1<<<1024, 256, 0, stream>>>(inp, tgt, colpart, rowsum64, (float*)d_out);
    k_stage2<<<128, 256, 0, stream>>>(colpart, rowsum64, wgt, (float*)d_out);
}

// Round 11
// 154.182 us; speedup vs baseline: 1.0589x; 1.0576x over previous
//
#include <hip/hip_runtime.h>

#define WW 512
#define HH 512
#define NPLANES 64   // B*C = 16*4
#define NCH 4
#define NSTRIP 8     // 64-row strips per plane (4 waves x 16 rows per block)

// e(x) = 2^(-14.43*x + 7.21); sigmoid((x-0.5)*10) = 1/(1+e(x))
__device__ __forceinline__ float expu(float x) {
    return __builtin_amdgcn_exp2f(__builtin_fmaf(x, -14.4269504089f, 7.2134752044f));
}
__device__ __forceinline__ float sigf(float x) {          // prologue only
    return __builtin_amdgcn_rcpf(1.0f + expu(x));
}
// sum of 1/p_i over 4 values with ONE rcp
__device__ __forceinline__ float sum4sig(float p0, float p1, float p2, float p3) {
    float q01 = p0 * p1, q23 = p2 * p3;
    float inv = __builtin_amdgcn_rcpf(q01 * q23);
    return __builtin_fmaf(p0 + p1, q23, (p2 + p3) * q01) * inv;
}
// individual reciprocals of 4 values with ONE rcp (batch inversion)
__device__ __forceinline__ void inv4(float p0, float p1, float p2, float p3,
                                     float& r0, float& r1, float& r2, float& r3) {
    float q01 = p0 * p1, q23 = p2 * p3;
    float inv = __builtin_amdgcn_rcpf(q01 * q23);
    float i01 = q23 * inv, i23 = q01 * inv;   // 1/(p0 p1), 1/(p2 p3)
    r0 = p1 * i01; r1 = p0 * i01;
    r2 = p3 * i23; r3 = p2 * i23;
}

// Stage 1 -- FINAL: session-best configuration (R3, measured 154.0 us total,
// stage1 49.3-52.8 us, VGPR 32). 10-round ledger: occupancy x2, trans -37%,
// VALU -22%, 1-deep prefetch, L3-resident inputs, zero-DS loop, instruction
// diet, trans->VALU poly offload -- all null or regressions vs this shape.
// The ~50us stage1 floor's mechanism is not visible in available counters
// (no pipe >50%, HBM 20%, latency excluded by L3-resident invariance).
__global__ __launch_bounds__(256, 4)
void k_stage1(const float* __restrict__ inp, const float* __restrict__ tgt,
              float* __restrict__ colpart, float* __restrict__ rowsum8,
              float* __restrict__ out) {
    const int bid    = blockIdx.x;
    const int tensor = bid >> 9;          // 0..1
    const int plane  = (bid >> 3) & 63;   // 0..63
    const int s      = bid & 7;           // 0..7 (64-row strip)
    const int tid    = threadIdx.x;
    const int wave   = tid >> 6;          // 0..3
    const int lane   = tid & 63;

    if (bid == 0 && tid == 0) out[0] = 0.0f;  // zero-init for stage-2 atomics

    const float* __restrict__ base =
        (tensor == 0 ? inp : tgt) + (size_t)plane * (HH * WW);
    const int r0    = s * 64 + wave * 16;
    const int r1    = r0 + 16;
    const int cbase = lane * 8;

    float prev[8], cur[8], cacc[8];
    #pragma unroll
    for (int k = 0; k < 8; ++k) cacc[k] = 0.0f;

    // prologue: prev = sig(row r0-1) (zero-pad), cur = sig(row r0)
    if (r0 == 0) {
        #pragma unroll
        for (int k = 0; k < 8; ++k) prev[k] = 0.0f;
    } else {
        const float4* p4 = reinterpret_cast<const float4*>(base + (size_t)(r0 - 1) * WW + cbase);
        float4 a = p4[0], b = p4[1];
        prev[0]=sigf(a.x); prev[1]=sigf(a.y); prev[2]=sigf(a.z); prev[3]=sigf(a.w);
        prev[4]=sigf(b.x); prev[5]=sigf(b.y); prev[6]=sigf(b.z); prev[7]=sigf(b.w);
    }
    {
        const float4* p4 = reinterpret_cast<const float4*>(base + (size_t)r0 * WW + cbase);
        float4 a = p4[0], b = p4[1];
        cur[0]=sigf(a.x); cur[1]=sigf(a.y); cur[2]=sigf(a.z); cur[3]=sigf(a.w);
        cur[4]=sigf(b.x); cur[5]=sigf(b.y); cur[6]=sigf(b.z); cur[7]=sigf(b.w);
    }

    float* __restrict__ rs_out =
        rowsum8 + ((size_t)tensor * NPLANES + plane) * (HH * 8);

    // strength-reduced row pointer for the (r+1) load
    const float* rowp = base + (size_t)(r0 + 1) * WW + cbase;

    for (int r = r0; r < r1; ++r, rowp += WW) {
        // 1) issue next-row loads FIRST (raw; convert later)
        float4 a, b;
        if (r + 1 < HH) {
            const float4* p4 = reinterpret_cast<const float4*>(rowp);
            a = p4[0]; b = p4[1];
        } else {
            a = make_float4(0.f,0.f,0.f,0.f); b = a;
        }

        // 2) horizontal bounds on row r (edge vals cross-lane); row sum needs
        //    only the SUM of 8 sigmoids -> 8 exp + 2 rcp
        float lv = __shfl_up(cur[7], 1);
        if (lane == 0)  lv = 0.0f;   // zero-pad col -1
        float rv = __shfl_down(cur[0], 1);
        if (lane == 63) rv = 0.0f;   // zero-pad col W

        float h0 = 1.0f + expu(fabsf(cur[1] - lv));
        float h1 = 1.0f + expu(fabsf(cur[2] - cur[0]));
        float h2 = 1.0f + expu(fabsf(cur[3] - cur[1]));
        float h3 = 1.0f + expu(fabsf(cur[4] - cur[2]));
        float h4 = 1.0f + expu(fabsf(cur[5] - cur[3]));
        float h5 = 1.0f + expu(fabsf(cur[6] - cur[4]));
        float h6 = 1.0f + expu(fabsf(cur[7] - cur[5]));
        float h7 = 1.0f + expu(fabsf(rv     - cur[6]));
        float hp = sum4sig(h0, h1, h2, h3) + sum4sig(h4, h5, h6, h7);

        // 3-step butterfly: lanes 0..7 hold 8 partials covering the full row.
        hp += __shfl_xor(hp, 8);
        hp += __shfl_xor(hp, 16);
        hp += __shfl_xor(hp, 32);
        if (lane < 8) rs_out[(size_t)r * 8 + lane] = hp;

        // 3) convert loaded row via batch inversion: 8 exp + 2 rcp
        float nxt[8];
        if (r + 1 < HH) {
            float p0 = 1.0f + expu(a.x), p1 = 1.0f + expu(a.y);
            float p2 = 1.0f + expu(a.z), p3 = 1.0f + expu(a.w);
            float p4_ = 1.0f + expu(b.x), p5 = 1.0f + expu(b.y);
            float p6 = 1.0f + expu(b.z), p7 = 1.0f + expu(b.w);
            inv4(p0, p1, p2, p3, nxt[0], nxt[1], nxt[2], nxt[3]);
            inv4(p4_, p5, p6, p7, nxt[4], nxt[5], nxt[6], nxt[7]);
        } else {
            #pragma unroll
            for (int k = 0; k < 8; ++k) nxt[k] = 0.0f;  // zero-pad row H
        }

        // 4) vertical bounds: individual values per column accumulator;
        //    batch inversion again: 8 exp + 2 rcp
        {
            float v0 = 1.0f + expu(fabsf(nxt[0] - prev[0]));
            float v1 = 1.0f + expu(fabsf(nxt[1] - prev[1]));
            float v2 = 1.0f + expu(fabsf(nxt[2] - prev[2]));
            float v3 = 1.0f + expu(fabsf(nxt[3] - prev[3]));
            float v4 = 1.0f + expu(fabsf(nxt[4] - prev[4]));
            float v5 = 1.0f + expu(fabsf(nxt[5] - prev[5]));
            float v6 = 1.0f + expu(fabsf(nxt[6] - prev[6]));
            float v7 = 1.0f + expu(fabsf(nxt[7] - prev[7]));
            float s0, s1, s2, s3, s4, s5, s6, s7;
            inv4(v0, v1, v2, v3, s0, s1, s2, s3);
            inv4(v4, v5, v6, v7, s4, s5, s6, s7);
            cacc[0] += s0; cacc[1] += s1; cacc[2] += s2; cacc[3] += s3;
            cacc[4] += s4; cacc[5] += s5; cacc[6] += s6; cacc[7] += s7;
        }

        // rotate window
        #pragma unroll
        for (int k = 0; k < 8; ++k) { prev[k] = cur[k]; cur[k] = nxt[k]; }
    }

    // combine column partials across the 4 waves of this block
    __shared__ float cl[4][WW];
    #pragma unroll
    for (int k = 0; k < 8; ++k) cl[wave][cbase + k] = cacc[k];
    __syncthreads();

    float* __restrict__ cp_out =
        colpart + (((size_t)tensor * NPLANES + plane) * NSTRIP + s) * WW;
    for (int c = tid; c < WW; c += 256)
        cp_out[c] = cl[0][c] + cl[1][c] + cl[2][c] + cl[3][c];
}

// logical sobel-source value: S(0)=512*sig(0), S(j)=sum[j-1], 0 outside [0,512)
__device__ __forceinline__ float Sval(const float* s, int j, float s0) {
    if (j < 0 || j >= 512) return 0.0f;
    if (j == 0) return s0;
    return s[j - 1];
}
__device__ __forceinline__ float term(const float* s, int j, float s0) {
    return fabsf(Sval(s, j + 1, s0) - Sval(s, j - 1, s0));
}

// Stage 2 (merged with mean): one block per plane; finalize col/row sums,
// sobel+abs+sum both directions for both tensors, atomicAdd mean contribution.
__global__ __launch_bounds__(256)
void k_stage2(const float* __restrict__ colpart, const float* __restrict__ rowsum8,
              const float* __restrict__ weight, float* __restrict__ out) {
    __shared__ float cI[WW], cT[WW], rI[WW], rT[WW];
    const int p   = blockIdx.x;   // plane = b*4 + c
    const int tid = threadIdx.x;

    for (int c = tid; c < WW; c += 256) {
        const float* a = colpart + (((size_t)0 * NPLANES + p) * NSTRIP) * WW + c;
        const float* b = colpart + (((size_t)1 * NPLANES + p) * NSTRIP) * WW + c;
        float sa = 0.f, sb = 0.f;
        #pragma unroll
        for (int i = 0; i < NSTRIP; ++i) { sa += a[i * WW]; sb += b[i * WW]; }
        cI[c] = sa;
        cT[c] = sb;
        const float* ra = rowsum8 + ((size_t)0 * NPLANES + p) * (HH * 8) + (size_t)c * 8;
        const float* rb = rowsum8 + ((size_t)1 * NPLANES + p) * (HH * 8) + (size_t)c * 8;
        float sra = 0.f, srb = 0.f;
        #pragma unroll
        for (int i = 0; i < 8; ++i) { sra += ra[i]; srb += rb[i]; }
        rI[c] = sra;
        rT[c] = srb;
    }
    __syncthreads();

    // 512 * sigmoid(-5)
    const float s0 = 3.4267396732f;

    float sIx = 0.f, sTx = 0.f, sIy = 0.f, sTy = 0.f;
    for (int j = tid; j < WW; j += 256) {
        sIx += term(cI, j, s0);
        sTx += term(cT, j, s0);
        sIy += term(rI, j, s0);
        sTy += term(rT, j, s0);
    }
    #pragma unroll
    for (int off = 32; off >= 1; off >>= 1) {
        sIx += __shfl_xor(sIx, off);
        sTx += __shfl_xor(sTx, off);
        sIy += __shfl_xor(sIy, off);
        sTy += __shfl_xor(sTy, off);
    }
    __shared__ float red[4][4];
    const int wave = tid >> 6, lane = tid & 63;
    if (lane == 0) {
        red[wave][0] = sIx; red[wave][1] = sTx;
        red[wave][2] = sIy; red[wave][3] = sTy;
    }
    __syncthreads();
    if (tid == 0) {
        float Ix = 0.f, Tx = 0.f, Iy = 0.f, Ty = 0.f;
        for (int w2 = 0; w2 < 4; ++w2) {
            Ix += red[w2][0]; Tx += red[w2][1];
            Iy += red[w2][2]; Ty += red[w2][3];
        }
        Ix *= 0.25f; Tx *= 0.25f; Iy *= 0.25f; Ty *= 0.25f;
        const float wgt = weight[p & (NCH - 1)];
        float loss = 0.5f * (fabsf((Ix - Tx) * wgt) + fabsf((Iy - Ty) * wgt));
        atomicAdd(out, loss * (1.0f / NPLANES));
    }
}

extern "C" void kernel_launch(void* const* d_in, const int* in_sizes, int n_in,
                              void* d_out, int out_size, void* d_ws, size_t ws_size,
                              hipStream_t stream) {
    const float* inp = (const float*)d_in[0];
    const float* tgt = (const float*)d_in[1];
    const float* wgt = (const float*)d_in[2];
    float* ws = (float*)d_ws;

    // ws layout (floats):
    float* colpart = ws;                       // [2][64][8][512]  = 524288
    float* rowsum8 = ws + 524288;              // [2][64][512][8]  = 524288

    k_stage1<<<1024, 256, 0, stream>>>(inp, tgt, colpart, rowsum8, (float*)d_out);
    k_stage2<<<64, 256, 0, stream>>>(colpart, rowsum8, wgt, (float*)d_out);
}